// Round 3
// baseline (1092.717 us; speedup 1.0000x reference)
//
#include <hip/hip_runtime.h>
#include <math.h>

#define D 128
#define H 256

typedef short s16x8 __attribute__((ext_vector_type(8)));  // 8 bf16 bit-patterns (4 VGPRs)
typedef float f32x4 __attribute__((ext_vector_type(4)));
typedef unsigned short u16;
typedef unsigned int u32;

// float -> bf16 (round-nearest-even) as bit pattern
__device__ __forceinline__ u16 f2b(float f) {
    union { float f; unsigned u; } c;
    c.f = f;
    unsigned u = c.u + 0x7FFFu + ((c.u >> 16) & 1u);
    return (u16)(u >> 16);
}
__device__ __forceinline__ float b2f(u16 h) {
    union { unsigned u; float f; } c;
    c.u = ((unsigned)h) << 16;
    return c.f;
}
__device__ __forceinline__ float blo(u32 p) {   // bf16 in low half
    union { unsigned u; float f; } c;
    c.u = p << 16;
    return c.f;
}
__device__ __forceinline__ float bhi(u32 p) {   // bf16 in high half
    union { unsigned u; float f; } c;
    c.u = p & 0xFFFF0000u;
    return c.f;
}

// ---------------- CSR build ----------------

__global__ __launch_bounds__(256) void k_count(const int* __restrict__ dstA,
                                               int* __restrict__ deg, int E) {
    int e = blockIdx.x * 256 + threadIdx.x;
    if (e < E) atomicAdd(&deg[dstA[e]], 1);
}

// 3-phase hierarchical exclusive scan.
__global__ __launch_bounds__(1024) void k_scan1(const int* __restrict__ deg,
                                                int* __restrict__ rowptr,
                                                int* __restrict__ bsum, int N) {
    __shared__ int tmp[1024];
    int t = threadIdx.x;
    int i = blockIdx.x * 1024 + t;
    int v = (i < N) ? deg[i] : 0;
    tmp[t] = v;
    __syncthreads();
    #pragma unroll
    for (int off = 1; off < 1024; off <<= 1) {
        int u = (t >= off) ? tmp[t - off] : 0;
        __syncthreads();
        tmp[t] += u;
        __syncthreads();
    }
    if (i < N) rowptr[i] = tmp[t] - v;      // exclusive within block
    if (t == 1023) bsum[blockIdx.x] = tmp[1023];
}

__global__ __launch_bounds__(1024) void k_scan2(int* __restrict__ bsum, int B) {
    __shared__ int sums[1024];
    int t = threadIdx.x;
    int chunk = (B + 1023) >> 10;
    int beg = t * chunk;
    int end = beg + chunk;
    if (end > B) end = B;
    int s = 0;
    for (int i = beg; i < end; ++i) s += bsum[i];
    sums[t] = s;
    __syncthreads();
    #pragma unroll
    for (int off = 1; off < 1024; off <<= 1) {
        int v = (t >= off) ? sums[t - off] : 0;
        __syncthreads();
        sums[t] += v;
        __syncthreads();
    }
    int run = (t == 0) ? 0 : sums[t - 1];
    for (int i = beg; i < end; ++i) {
        int v = bsum[i];
        bsum[i] = run;
        run += v;
    }
}

__global__ __launch_bounds__(1024) void k_scan3(int* __restrict__ rowptr,
                                                const int* __restrict__ bsum,
                                                int N, int E) {
    int i = blockIdx.x * 1024 + threadIdx.x;
    if (i < N) rowptr[i] += bsum[blockIdx.x];
    else if (i == N) rowptr[N] = E;
}

__global__ __launch_bounds__(256) void k_scatter(const int* __restrict__ srcA,
                                                 const int* __restrict__ dstA,
                                                 const int* __restrict__ rowptr,
                                                 int* __restrict__ cnt,
                                                 int* __restrict__ srcs, int E) {
    int e = blockIdx.x * 256 + threadIdx.x;
    if (e < E) {
        int d = dstA[e];
        int p = rowptr[d] + atomicAdd(&cnt[d], 1);
        srcs[p] = srcA[e];
    }
}

// ---------------- prep: fp32 -> bf16 casts & weight transpose ----------------

__global__ __launch_bounds__(256) void k_cvt(const float* __restrict__ x,
                                             u16* __restrict__ xb, int n4) {
    int i = blockIdx.x * 256 + threadIdx.x;
    if (i < n4) {
        float4 v = ((const float4*)x)[i];
        xb[i * 4 + 0] = f2b(v.x);
        xb[i * 4 + 1] = f2b(v.y);
        xb[i * 4 + 2] = f2b(v.z);
        xb[i * 4 + 3] = f2b(v.w);
    }
}

// WT1[l][n(256)][k(128)] = W1[l][k][n];  WT2[l][n(128)][k(256)] = W2[l][k][n]
__global__ __launch_bounds__(256) void k_prep(const float* __restrict__ W1_all,
                                              const float* __restrict__ W2_all,
                                              u16* __restrict__ WT1,
                                              u16* __restrict__ WT2) {
    int id = blockIdx.x * 256 + threadIdx.x;   // 262144 total
    if (id < 131072) {
        int l = id >> 15, rem = id & 32767, n = rem >> 7, k = rem & 127;
        WT1[id] = f2b(W1_all[l * 32768 + k * 256 + n]);
    } else {
        int id2 = id - 131072;
        int l = id2 >> 15, rem = id2 & 32767, n = rem >> 8, k = rem & 255;
        WT2[id2] = f2b(W2_all[l * 32768 + k * 128 + n]);
    }
}

// ---------------- edge softmax-aggregation ----------------
// v3: 4 nodes per WAVE (16 per block). The v2 kernel was phase-latency-bound:
// each wave owned one node (avg deg 8 = one gather group), so its life was
// ~4 dependent memory phases (rowptr -> srcs -> gathers -> own row) with only
// ~300cyc of VALU. Now one wave interleaves 4 independent node chains:
// one coalesced rowptr load (lanes 0..4 + shfl), 4 independent srcs loads,
// 4 own-row prefetches, and up to 32 outstanding row gathers.
// Math unchanged: fast path + wave-voted exact-online fallback.

__global__ __launch_bounds__(256) void k_edge(const u16* __restrict__ hin,
                                              const int* __restrict__ rowptr,
                                              const int* __restrict__ srcs,
                                              const float* __restrict__ tptr,
                                              u16* __restrict__ g,
                                              float* __restrict__ bnsum,
                                              float* __restrict__ bnss, int N) {
    if (blockIdx.x == 0) {       // zero BN partial buffers for this layer's mm1
        bnsum[threadIdx.x] = 0.f;
        bnss[threadIdx.x] = 0.f;
    }
    int w = threadIdx.x >> 6;
    int lane = threadIdx.x & 63;
    int wbase = blockIdx.x * 16 + w * 4;     // first of this wave's 4 nodes
    if (wbase >= N) return;
    const u32* hin32 = (const u32*)hin;
    float t = *tptr;

    // one coalesced load covers rowptr[wbase .. wbase+4]
    int rp = 0;
    if (lane <= 4 && wbase + lane <= N) rp = rowptr[wbase + lane];

    int beg[4], cnt[4];
    u32 pu[4];
    int maxcnt = 0;
    #pragma unroll
    for (int i = 0; i < 4; ++i) {
        int b = __shfl(rp, i);
        int e = __shfl(rp, i + 1);
        bool valid = (wbase + i < N);
        beg[i] = b;
        cnt[i] = valid ? (e - b) : 0;
        if (cnt[i] > maxcnt) maxcnt = cnt[i];
        // prefetch own row (independent load, issued early)
        pu[i] = valid ? hin32[(size_t)(wbase + i) * 64 + lane] : 0u;
    }

    float s0a[4], s1a[4], sn0a[4], sn1a[4], mxa[4], mva[4];
    #pragma unroll
    for (int i = 0; i < 4; ++i) {
        s0a[i] = s1a[i] = sn0a[i] = sn1a[i] = 0.f;
        mxa[i] = -3.0e38f;
        mva[i] = 0.f;
    }

    for (int b64 = 0; b64 < maxcnt; b64 += 64) {
        // coalesced src-index rows: lane l holds index of edge (b64+l) of node i
        int sv[4];
        #pragma unroll
        for (int i = 0; i < 4; ++i)
            sv[i] = (b64 + lane < cnt[i]) ? srcs[beg[i] + b64 + lane] : 0;

        int innerEnd = maxcnt - b64;
        if (innerEnd > 64) innerEnd = 64;
        for (int ib = 0; ib < innerEnd; ib += 8) {
            u32 pr[4][8];
            int m[4];
            #pragma unroll
            for (int i = 0; i < 4; ++i) {
                int rem = cnt[i] - b64 - ib;
                m[i] = rem < 0 ? 0 : (rem > 8 ? 8 : rem);
                #pragma unroll
                for (int j = 0; j < 8; ++j) {
                    if (j < m[i]) {
                        int vi = __shfl(sv[i], ib + j);
                        pr[i][j] = hin32[(size_t)vi * 64 + lane];
                    }
                }
            }
            #pragma unroll
            for (int i = 0; i < 4; ++i) {
                #pragma unroll
                for (int j = 0; j < 8; ++j) {
                    if (j < m[i]) {
                        u32 p = pr[i][j];
                        float v0 = fmaxf(blo(p), 0.f) + 1e-7f;
                        float v1 = fmaxf(bhi(p), 0.f) + 1e-7f;
                        float l0 = v0 * t, l1 = v1 * t;
                        mxa[i] = fmaxf(mxa[i], fmaxf(l0, l1));
                        mva[i] = fmaxf(mva[i], fmaxf(v0, v1));
                        float w0 = __expf(l0), w1 = __expf(l1);
                        s0a[i] += w0; s1a[i] += w1;
                        sn0a[i] = fmaf(w0, v0, sn0a[i]);
                        sn1a[i] = fmaf(w1, v1, sn1a[i]);
                    }
                }
            }
        }
    }

    bool bad = false;
    #pragma unroll
    for (int i = 0; i < 4; ++i)
        bad = bad || (cnt[i] > 0 && (mxa[i] > 60.f || mxa[i] < -20.f || mva[i] > 1.0e10f));
    if (__any(bad)) {
        // exact online-softmax fallback (rare; correct for any t / magnitudes)
        #pragma unroll
        for (int i = 0; i < 4; ++i) {
            float m0 = -3.0e38f, m1 = -3.0e38f;
            float s0 = 0.f, s1 = 0.f, sn0 = 0.f, sn1 = 0.f;
            for (int e = beg[i]; e < beg[i] + cnt[i]; ++e) {
                int v = srcs[e];
                u32 p = hin32[(size_t)v * 64 + lane];
                float v0 = fmaxf(blo(p), 0.f) + 1e-7f;
                float v1 = fmaxf(bhi(p), 0.f) + 1e-7f;
                float l0 = v0 * t, l1 = v1 * t;
                float nm0 = fmaxf(m0, l0), nm1 = fmaxf(m1, l1);
                float a0 = __expf(m0 - nm0), a1 = __expf(m1 - nm1);
                float w0 = __expf(l0 - nm0), w1 = __expf(l1 - nm1);
                s0 = s0 * a0 + w0;           s1 = s1 * a1 + w1;
                sn0 = sn0 * a0 + w0 * v0;    sn1 = sn1 * a1 + w1 * v1;
                m0 = nm0; m1 = nm1;
            }
            s0a[i] = s0; s1a[i] = s1; sn0a[i] = sn0; sn1a[i] = sn1;
        }
    }

    #pragma unroll
    for (int i = 0; i < 4; ++i) {
        if (wbase + i < N) {
            float aggr0 = sn0a[i] / (s0a[i] + 1e-16f);
            float aggr1 = sn1a[i] / (s1a[i] + 1e-16f);
            float o0 = aggr0 + blo(pu[i]);
            float o1 = aggr1 + bhi(pu[i]);
            ((u32*)g)[(size_t)(wbase + i) * 64 + lane] =
                (u32)f2b(o0) | ((u32)f2b(o1) << 16);
        }
    }
}

// ---------------- mm1: h1 = g @ W1 (bf16 MFMA), fused BN partials ----------------
// 128x128 tile, 256 threads (4 waves), BK=64 chunks, K=128.

__global__ __launch_bounds__(256) void k_mm1(const u16* __restrict__ A,
                                             const u16* __restrict__ WT,
                                             u16* __restrict__ C,
                                             float* __restrict__ bnsum,
                                             float* __restrict__ bnss, int M) {
    __shared__ u16 As[128][72];   // stride 144B: 2-way bank alias (free)
    __shared__ u16 Bs[128][72];
    __shared__ float csum[128], css[128];
    int row0 = blockIdx.x * 128, n0 = blockIdx.y * 128;
    int tid = threadIdx.x;
    int lane = tid & 63, w = tid >> 6;
    int r0w = (w & 1) * 64, c0w = (w >> 1) * 64;
    int q = lane >> 4, ml = lane & 15;

    if (tid < 128) { csum[tid] = 0.f; css[tid] = 0.f; }

    f32x4 acc[4][4];
    #pragma unroll
    for (int i = 0; i < 4; ++i)
        #pragma unroll
        for (int j = 0; j < 4; ++j) acc[i][j] = f32x4{0.f, 0.f, 0.f, 0.f};

    for (int kk = 0; kk < 128; kk += 64) {
        #pragma unroll
        for (int i = 0; i < 4; ++i) {
            int r = i * 32 + (tid >> 3);
            int c8 = (tid & 7) * 8;
            s16x8 va = s16x8{0, 0, 0, 0, 0, 0, 0, 0};
            if (row0 + r < M)
                va = *reinterpret_cast<const s16x8*>(&A[(size_t)(row0 + r) * 128 + kk + c8]);
            *reinterpret_cast<s16x8*>(&As[r][c8]) = va;
            s16x8 vb = *reinterpret_cast<const s16x8*>(&WT[(size_t)(n0 + r) * 128 + kk + c8]);
            *reinterpret_cast<s16x8*>(&Bs[r][c8]) = vb;
        }
        __syncthreads();
        #pragma unroll
        for (int ks = 0; ks < 64; ks += 32) {
            s16x8 af[4], bfr[4];
            #pragma unroll
            for (int rt = 0; rt < 4; ++rt)
                af[rt] = *reinterpret_cast<const s16x8*>(&As[r0w + rt * 16 + ml][ks + q * 8]);
            #pragma unroll
            for (int ct = 0; ct < 4; ++ct)
                bfr[ct] = *reinterpret_cast<const s16x8*>(&Bs[c0w + ct * 16 + ml][ks + q * 8]);
            #pragma unroll
            for (int rt = 0; rt < 4; ++rt)
                #pragma unroll
                for (int ct = 0; ct < 4; ++ct)
                    acc[rt][ct] = __builtin_amdgcn_mfma_f32_16x16x32_bf16(
                        af[rt], bfr[ct], acc[rt][ct], 0, 0, 0);
        }
        __syncthreads();
    }

    #pragma unroll
    for (int ct = 0; ct < 4; ++ct) {
        float s = 0.f, ss = 0.f;
        int col = n0 + c0w + ct * 16 + ml;
        #pragma unroll
        for (int rt = 0; rt < 4; ++rt) {
            int rbase = row0 + r0w + rt * 16 + q * 4;
            #pragma unroll
            for (int rg = 0; rg < 4; ++rg) {
                float v = acc[rt][ct][rg];
                s += v;
                ss += v * v;
                if (rbase + rg < M)
                    C[(size_t)(rbase + rg) * H + col] = f2b(v);
            }
        }
        atomicAdd(&csum[c0w + ct * 16 + ml], s);
        atomicAdd(&css[c0w + ct * 16 + ml], ss);
    }
    __syncthreads();
    if (tid < 128) {
        atomicAdd(&bnsum[n0 + tid], csum[tid]);
        atomicAdd(&bnss[n0 + tid], css[tid]);
    }
}

// ---------------- BN finalize ----------------

__global__ __launch_bounds__(256) void k_bnfin(const float* __restrict__ bnsum,
                                               const float* __restrict__ bnss,
                                               const float* __restrict__ gamma,
                                               const float* __restrict__ beta,
                                               float* __restrict__ scale,
                                               float* __restrict__ shift, int M) {
    int c = threadIdx.x;
    float inv = 1.0f / (float)M;
    float mean = bnsum[c] * inv;
    float var = bnss[c] * inv - mean * mean;
    if (var < 0.f) var = 0.f;
    float rstd = rsqrtf(var + 1e-5f);
    float sc = rstd * gamma[c];
    scale[c] = sc;
    shift[c] = beta[c] - mean * sc;
}

// ---------------- mm2: out = relu(norm(h1)) @ W2 (norm fused in A-stage) ----------------

__global__ __launch_bounds__(256) void k_mm2(const u16* __restrict__ H1,
                                             const float* __restrict__ scale,
                                             const float* __restrict__ shift,
                                             const u16* __restrict__ WT,
                                             float* __restrict__ outf,
                                             u16* __restrict__ outb, int M) {
    __shared__ u16 As[128][72];
    __shared__ u16 Bs[128][72];
    int row0 = blockIdx.x * 128;
    int tid = threadIdx.x;
    int lane = tid & 63, w = tid >> 6;
    int r0w = (w & 1) * 64, c0w = (w >> 1) * 64;
    int q = lane >> 4, ml = lane & 15;

    f32x4 acc[4][4];
    #pragma unroll
    for (int i = 0; i < 4; ++i)
        #pragma unroll
        for (int j = 0; j < 4; ++j) acc[i][j] = f32x4{0.f, 0.f, 0.f, 0.f};

    for (int kk = 0; kk < 256; kk += 64) {
        #pragma unroll
        for (int i = 0; i < 4; ++i) {
            int r = i * 32 + (tid >> 3);
            int c8 = (tid & 7) * 8;
            s16x8 o = s16x8{0, 0, 0, 0, 0, 0, 0, 0};
            if (row0 + r < M) {
                s16x8 v = *reinterpret_cast<const s16x8*>(&H1[(size_t)(row0 + r) * H + kk + c8]);
                #pragma unroll
                for (int j = 0; j < 8; ++j) {
                    float f = b2f((u16)v[j]) * scale[kk + c8 + j] + shift[kk + c8 + j];
                    o[j] = (short)f2b(fmaxf(f, 0.f));
                }
            }
            *reinterpret_cast<s16x8*>(&As[r][c8]) = o;
            s16x8 vb = *reinterpret_cast<const s16x8*>(&WT[(size_t)r * H + kk + c8]);
            *reinterpret_cast<s16x8*>(&Bs[r][c8]) = vb;
        }
        __syncthreads();
        #pragma unroll
        for (int ks = 0; ks < 64; ks += 32) {
            s16x8 af[4], bfr[4];
            #pragma unroll
            for (int rt = 0; rt < 4; ++rt)
                af[rt] = *reinterpret_cast<const s16x8*>(&As[r0w + rt * 16 + ml][ks + q * 8]);
            #pragma unroll
            for (int ct = 0; ct < 4; ++ct)
                bfr[ct] = *reinterpret_cast<const s16x8*>(&Bs[c0w + ct * 16 + ml][ks + q * 8]);
            #pragma unroll
            for (int rt = 0; rt < 4; ++rt)
                #pragma unroll
                for (int ct = 0; ct < 4; ++ct)
                    acc[rt][ct] = __builtin_amdgcn_mfma_f32_16x16x32_bf16(
                        af[rt], bfr[ct], acc[rt][ct], 0, 0, 0);
        }
        __syncthreads();
    }

    #pragma unroll
    for (int ct = 0; ct < 4; ++ct) {
        int col = c0w + ct * 16 + ml;
        #pragma unroll
        for (int rt = 0; rt < 4; ++rt) {
            int rbase = row0 + r0w + rt * 16 + q * 4;
            #pragma unroll
            for (int rg = 0; rg < 4; ++rg) {
                if (rbase + rg < M) {
                    float v = acc[rt][ct][rg];
                    if (outb)
                        outb[(size_t)(rbase + rg) * D + col] = f2b(fmaxf(v, 0.f));
                    else
                        outf[(size_t)(rbase + rg) * D + col] = v;
                }
            }
        }
    }
}

// ---------------- host launch ----------------

extern "C" void kernel_launch(void* const* d_in, const int* in_sizes, int n_in,
                              void* d_out, int out_size, void* d_ws, size_t ws_size,
                              hipStream_t stream) {
    const float* x         = (const float*)d_in[0];
    const int*   ei        = (const int*)d_in[1];
    const float* t_all     = (const float*)d_in[2];
    const float* W1_all    = (const float*)d_in[3];
    const float* W2_all    = (const float*)d_in[4];
    const float* gamma_all = (const float*)d_in[5];
    const float* beta_all  = (const float*)d_in[6];

    int N = in_sizes[0] / D;
    int E = in_sizes[1] / 2;
    float* out = (float*)d_out;

    char* ws = (char*)d_ws;
    size_t off = 0;
    auto alloc = [&](size_t bytes) -> void* {
        void* p = ws + off;
        off += (bytes + 255) & ~(size_t)255;
        return p;
    };
    int B = (N + 1023) >> 10;   // scan blocks
    int* rowptr = (int*)alloc((size_t)(N + 1) * 4);
    int* deg    = (int*)alloc((size_t)N * 4);
    int* srcs   = (int*)alloc((size_t)E * 4);
    int* bsum   = (int*)alloc((size_t)(B + 1) * 4);
    u16* xb     = (u16*)alloc((size_t)N * D * 2);
    u16* a0     = (u16*)alloc((size_t)N * D * 2);
    u16* a1     = (u16*)alloc((size_t)N * D * 2);
    u16* g      = (u16*)alloc((size_t)N * D * 2);
    u16* h1     = (u16*)alloc((size_t)N * H * 2);
    u16* WT1    = (u16*)alloc((size_t)4 * H * D * 2);
    u16* WT2    = (u16*)alloc((size_t)4 * D * H * 2);
    float* bnsum = (float*)alloc(H * 4);
    float* bnss  = (float*)alloc(H * 4);
    float* scale = (float*)alloc(H * 4);
    float* shift = (float*)alloc(H * 4);
    (void)ws_size; (void)n_in; (void)out_size;

    const int* srcA = ei;
    const int* dstA = ei + E;

    // prep: bf16 casts + weight transposes
    k_cvt<<<(N * D / 4 + 255) / 256, 256, 0, stream>>>(x, xb, N * D / 4);
    k_prep<<<1024, 256, 0, stream>>>(W1_all, W2_all, WT1, WT2);

    // CSR build (hierarchical 3-phase scan)
    hipMemsetAsync(deg, 0, (size_t)N * 4, stream);
    k_count<<<(E + 255) / 256, 256, 0, stream>>>(dstA, deg, E);
    k_scan1<<<B, 1024, 0, stream>>>(deg, rowptr, bsum, N);
    k_scan2<<<1, 1024, 0, stream>>>(bsum, B);
    k_scan3<<<(N + 1 + 1023) / 1024, 1024, 0, stream>>>(rowptr, bsum, N, E);
    hipMemsetAsync(deg, 0, (size_t)N * 4, stream);
    k_scatter<<<(E + 255) / 256, 256, 0, stream>>>(srcA, dstA, rowptr, deg, srcs, E);

    float* out0 = out;                  // mu
    float* out1 = out + (size_t)N * D;  // logstd

    int gx = (N + 127) / 128;
    for (int layer = 0; layer < 4; ++layer) {
        const u16* hin = (layer == 0) ? xb : (layer == 1 ? a0 : a1);
        k_edge<<<(N + 15) / 16, 256, 0, stream>>>(hin, rowptr, srcs, t_all + layer,
                                                  g, bnsum, bnss, N);

        k_mm1<<<dim3(gx, 2), 256, 0, stream>>>(g, WT1 + (size_t)layer * H * D, h1,
                                               bnsum, bnss, N);
        k_bnfin<<<1, H, 0, stream>>>(bnsum, bnss, gamma_all + (size_t)layer * H,
                                     beta_all + (size_t)layer * H, scale, shift, N);

        float* outf = nullptr;
        u16*   outb = nullptr;
        if (layer == 0)      outb = a0;
        else if (layer == 1) outb = a1;
        else if (layer == 2) outf = out0;
        else                 outf = out1;

        k_mm2<<<dim3(gx, 1), 256, 0, stream>>>(h1, scale, shift,
                                               WT2 + (size_t)layer * D * H,
                                               outf, outb, N);
    }
}

// Round 4
// 932.795 us; speedup vs baseline: 1.1714x; 1.1714x over previous
//
#include <hip/hip_runtime.h>
#include <math.h>

#define D 128
#define H 256

typedef short s16x8 __attribute__((ext_vector_type(8)));  // 8 bf16 bit-patterns (4 VGPRs)
typedef float f32x4 __attribute__((ext_vector_type(4)));
typedef unsigned short u16;
typedef unsigned int u32;

// float -> bf16 (round-nearest-even) as bit pattern
__device__ __forceinline__ u16 f2b(float f) {
    union { float f; unsigned u; } c;
    c.f = f;
    unsigned u = c.u + 0x7FFFu + ((c.u >> 16) & 1u);
    return (u16)(u >> 16);
}
__device__ __forceinline__ float b2f(u16 h) {
    union { unsigned u; float f; } c;
    c.u = ((unsigned)h) << 16;
    return c.f;
}
__device__ __forceinline__ float blo(u32 p) {   // bf16 in low half
    union { unsigned u; float f; } c;
    c.u = p << 16;
    return c.f;
}
__device__ __forceinline__ float bhi(u32 p) {   // bf16 in high half
    union { unsigned u; float f; } c;
    c.u = p & 0xFFFF0000u;
    return c.f;
}

// ---------------- CSR build ----------------

__global__ __launch_bounds__(256) void k_count(const int* __restrict__ dstA,
                                               int* __restrict__ deg, int E) {
    int e = blockIdx.x * 256 + threadIdx.x;
    if (e < E) atomicAdd(&deg[dstA[e]], 1);
}

// 3-phase hierarchical exclusive scan.
__global__ __launch_bounds__(1024) void k_scan1(const int* __restrict__ deg,
                                                int* __restrict__ rowptr,
                                                int* __restrict__ bsum, int N) {
    __shared__ int tmp[1024];
    int t = threadIdx.x;
    int i = blockIdx.x * 1024 + t;
    int v = (i < N) ? deg[i] : 0;
    tmp[t] = v;
    __syncthreads();
    #pragma unroll
    for (int off = 1; off < 1024; off <<= 1) {
        int u = (t >= off) ? tmp[t - off] : 0;
        __syncthreads();
        tmp[t] += u;
        __syncthreads();
    }
    if (i < N) rowptr[i] = tmp[t] - v;      // exclusive within block
    if (t == 1023) bsum[blockIdx.x] = tmp[1023];
}

__global__ __launch_bounds__(1024) void k_scan2(int* __restrict__ bsum, int B) {
    __shared__ int sums[1024];
    int t = threadIdx.x;
    int chunk = (B + 1023) >> 10;
    int beg = t * chunk;
    int end = beg + chunk;
    if (end > B) end = B;
    int s = 0;
    for (int i = beg; i < end; ++i) s += bsum[i];
    sums[t] = s;
    __syncthreads();
    #pragma unroll
    for (int off = 1; off < 1024; off <<= 1) {
        int v = (t >= off) ? sums[t - off] : 0;
        __syncthreads();
        sums[t] += v;
        __syncthreads();
    }
    int run = (t == 0) ? 0 : sums[t - 1];
    for (int i = beg; i < end; ++i) {
        int v = bsum[i];
        bsum[i] = run;
        run += v;
    }
}

__global__ __launch_bounds__(1024) void k_scan3(int* __restrict__ rowptr,
                                                const int* __restrict__ bsum,
                                                int N, int E) {
    int i = blockIdx.x * 1024 + threadIdx.x;
    if (i < N) rowptr[i] += bsum[blockIdx.x];
    else if (i == N) rowptr[N] = E;
}

__global__ __launch_bounds__(256) void k_scatter(const int* __restrict__ srcA,
                                                 const int* __restrict__ dstA,
                                                 const int* __restrict__ rowptr,
                                                 int* __restrict__ cnt,
                                                 int* __restrict__ srcs, int E) {
    int e = blockIdx.x * 256 + threadIdx.x;
    if (e < E) {
        int d = dstA[e];
        int p = rowptr[d] + atomicAdd(&cnt[d], 1);
        srcs[p] = srcA[e];
    }
}

// ---------------- prep: fp32 -> bf16 casts & weight transpose ----------------

__global__ __launch_bounds__(256) void k_cvt(const float* __restrict__ x,
                                             u16* __restrict__ xb, int n4) {
    int i = blockIdx.x * 256 + threadIdx.x;
    if (i < n4) {
        float4 v = ((const float4*)x)[i];
        xb[i * 4 + 0] = f2b(v.x);
        xb[i * 4 + 1] = f2b(v.y);
        xb[i * 4 + 2] = f2b(v.z);
        xb[i * 4 + 3] = f2b(v.w);
    }
}

// WT1[l][n(256)][k(128)] = W1[l][k][n];  WT2[l][n(128)][k(256)] = W2[l][k][n]
__global__ __launch_bounds__(256) void k_prep(const float* __restrict__ W1_all,
                                              const float* __restrict__ W2_all,
                                              u16* __restrict__ WT1,
                                              u16* __restrict__ WT2) {
    int id = blockIdx.x * 256 + threadIdx.x;   // 262144 total
    if (id < 131072) {
        int l = id >> 15, rem = id & 32767, n = rem >> 7, k = rem & 127;
        WT1[id] = f2b(W1_all[l * 32768 + k * 256 + n]);
    } else {
        int id2 = id - 131072;
        int l = id2 >> 15, rem = id2 & 32767, n = rem >> 8, k = rem & 255;
        WT2[id2] = f2b(W2_all[l * 32768 + k * 128 + n]);
    }
}

// ---------------- edge softmax-aggregation ----------------
// v4 = v2 structure (1 node/wave, proven 76us; v3's 4-node fattening regressed
// occupancy 68->36%) + three micro-fixes:
//  (1) broadcast src index via readlane -> SGPR -> scalar gather base
//      (kills ~5 VALU/gather of per-lane 64-bit addressing that __shfl forced)
//  (2) scalar rowptr loads (readfirstlane on u)
//  (3) 16-deep gather pipeline (covers ~93% of Poisson(8) degrees in one
//      flight) + own-row load hoisted before the loop.
// Math identical to v2: __expf fast path, wave-voted exact-online fallback.

__global__ __launch_bounds__(256) void k_edge(const u16* __restrict__ hin,
                                              const int* __restrict__ rowptr,
                                              const int* __restrict__ srcs,
                                              const float* __restrict__ tptr,
                                              u16* __restrict__ g,
                                              float* __restrict__ bnsum,
                                              float* __restrict__ bnss, int N) {
    if (blockIdx.x == 0) {       // zero BN partial buffers for this layer's mm1
        bnsum[threadIdx.x] = 0.f;
        bnss[threadIdx.x] = 0.f;
    }
    int u = blockIdx.x * 4 + (threadIdx.x >> 6);
    if (u >= N) return;
    u = __builtin_amdgcn_readfirstlane(u);   // wave-uniform -> SGPR
    int lane = threadIdx.x & 63;
    const u32* hin32 = (const u32*)hin;
    float t = *tptr;
    int beg = rowptr[u], end = rowptr[u + 1];   // scalar loads
    int cnt = end - beg;

    // own row: independent load, issued before the gather loop
    u32 pu = hin32[(size_t)u * 64 + lane];

    float s0 = 0.f, s1 = 0.f, sn0 = 0.f, sn1 = 0.f;
    float mx = -3.0e38f, mv = 0.f;

    for (int b = 0; b < cnt; b += 64) {
        int nb = cnt - b;
        if (nb > 64) nb = 64;
        // one coalesced load: lane l holds src index of edge (b+l)
        int sv = (b + lane < cnt) ? srcs[beg + b + lane] : 0;
        for (int ib = 0; ib < nb; ib += 16) {
            int m = nb - ib;
            if (m > 16) m = 16;
            u32 pr[16];
            #pragma unroll
            for (int j = 0; j < 16; ++j) {
                if (j < m) {
                    // uniform broadcast -> SGPR index -> scalar base address
                    int vi = __builtin_amdgcn_readlane(sv, ib + j);
                    pr[j] = hin32[(size_t)vi * 64 + lane];
                }
            }
            #pragma unroll
            for (int j = 0; j < 16; ++j) {
                if (j < m) {
                    u32 p = pr[j];
                    float v0 = fmaxf(blo(p), 0.f) + 1e-7f;
                    float v1 = fmaxf(bhi(p), 0.f) + 1e-7f;
                    float l0 = v0 * t, l1 = v1 * t;
                    mx = fmaxf(mx, fmaxf(l0, l1));
                    mv = fmaxf(mv, fmaxf(v0, v1));
                    float w0 = __expf(l0), w1 = __expf(l1);
                    s0 += w0; s1 += w1;
                    sn0 = fmaf(w0, v0, sn0);
                    sn1 = fmaf(w1, v1, sn1);
                }
            }
        }
    }

    bool has = (cnt > 0);
    if (__any(has && (mx > 60.f || mx < -20.f || mv > 1.0e10f))) {
        // exact online-softmax fallback (rare; correct for any t / magnitudes)
        float m0 = -3.0e38f, m1 = -3.0e38f;
        s0 = s1 = sn0 = sn1 = 0.f;
        for (int e = beg; e < end; ++e) {
            int v = srcs[e];
            u32 p = hin32[(size_t)v * 64 + lane];
            float v0 = fmaxf(blo(p), 0.f) + 1e-7f;
            float v1 = fmaxf(bhi(p), 0.f) + 1e-7f;
            float l0 = v0 * t, l1 = v1 * t;
            float nm0 = fmaxf(m0, l0), nm1 = fmaxf(m1, l1);
            float a0 = __expf(m0 - nm0), a1 = __expf(m1 - nm1);
            float w0 = __expf(l0 - nm0), w1 = __expf(l1 - nm1);
            s0 = s0 * a0 + w0;           s1 = s1 * a1 + w1;
            sn0 = sn0 * a0 + w0 * v0;    sn1 = sn1 * a1 + w1 * v1;
            m0 = nm0; m1 = nm1;
        }
    }

    float aggr0 = sn0 / (s0 + 1e-16f);
    float aggr1 = sn1 / (s1 + 1e-16f);
    float o0 = aggr0 + blo(pu);
    float o1 = aggr1 + bhi(pu);
    ((u32*)g)[(size_t)u * 64 + lane] = (u32)f2b(o0) | ((u32)f2b(o1) << 16);
}

// ---------------- mm1: h1 = g @ W1 (bf16 MFMA), fused BN partials ----------------
// 128x128 tile, 256 threads (4 waves), BK=64 chunks, K=128.

__global__ __launch_bounds__(256) void k_mm1(const u16* __restrict__ A,
                                             const u16* __restrict__ WT,
                                             u16* __restrict__ C,
                                             float* __restrict__ bnsum,
                                             float* __restrict__ bnss, int M) {
    __shared__ u16 As[128][72];   // stride 144B: 2-way bank alias (free)
    __shared__ u16 Bs[128][72];
    __shared__ float csum[128], css[128];
    int row0 = blockIdx.x * 128, n0 = blockIdx.y * 128;
    int tid = threadIdx.x;
    int lane = tid & 63, w = tid >> 6;
    int r0w = (w & 1) * 64, c0w = (w >> 1) * 64;
    int q = lane >> 4, ml = lane & 15;

    if (tid < 128) { csum[tid] = 0.f; css[tid] = 0.f; }

    f32x4 acc[4][4];
    #pragma unroll
    for (int i = 0; i < 4; ++i)
        #pragma unroll
        for (int j = 0; j < 4; ++j) acc[i][j] = f32x4{0.f, 0.f, 0.f, 0.f};

    for (int kk = 0; kk < 128; kk += 64) {
        #pragma unroll
        for (int i = 0; i < 4; ++i) {
            int r = i * 32 + (tid >> 3);
            int c8 = (tid & 7) * 8;
            s16x8 va = s16x8{0, 0, 0, 0, 0, 0, 0, 0};
            if (row0 + r < M)
                va = *reinterpret_cast<const s16x8*>(&A[(size_t)(row0 + r) * 128 + kk + c8]);
            *reinterpret_cast<s16x8*>(&As[r][c8]) = va;
            s16x8 vb = *reinterpret_cast<const s16x8*>(&WT[(size_t)(n0 + r) * 128 + kk + c8]);
            *reinterpret_cast<s16x8*>(&Bs[r][c8]) = vb;
        }
        __syncthreads();
        #pragma unroll
        for (int ks = 0; ks < 64; ks += 32) {
            s16x8 af[4], bfr[4];
            #pragma unroll
            for (int rt = 0; rt < 4; ++rt)
                af[rt] = *reinterpret_cast<const s16x8*>(&As[r0w + rt * 16 + ml][ks + q * 8]);
            #pragma unroll
            for (int ct = 0; ct < 4; ++ct)
                bfr[ct] = *reinterpret_cast<const s16x8*>(&Bs[c0w + ct * 16 + ml][ks + q * 8]);
            #pragma unroll
            for (int rt = 0; rt < 4; ++rt)
                #pragma unroll
                for (int ct = 0; ct < 4; ++ct)
                    acc[rt][ct] = __builtin_amdgcn_mfma_f32_16x16x32_bf16(
                        af[rt], bfr[ct], acc[rt][ct], 0, 0, 0);
        }
        __syncthreads();
    }

    #pragma unroll
    for (int ct = 0; ct < 4; ++ct) {
        float s = 0.f, ss = 0.f;
        int col = n0 + c0w + ct * 16 + ml;
        #pragma unroll
        for (int rt = 0; rt < 4; ++rt) {
            int rbase = row0 + r0w + rt * 16 + q * 4;
            #pragma unroll
            for (int rg = 0; rg < 4; ++rg) {
                float v = acc[rt][ct][rg];
                s += v;
                ss += v * v;
                if (rbase + rg < M)
                    C[(size_t)(rbase + rg) * H + col] = f2b(v);
            }
        }
        atomicAdd(&csum[c0w + ct * 16 + ml], s);
        atomicAdd(&css[c0w + ct * 16 + ml], ss);
    }
    __syncthreads();
    if (tid < 128) {
        atomicAdd(&bnsum[n0 + tid], csum[tid]);
        atomicAdd(&bnss[n0 + tid], css[tid]);
    }
}

// ---------------- BN finalize ----------------

__global__ __launch_bounds__(256) void k_bnfin(const float* __restrict__ bnsum,
                                               const float* __restrict__ bnss,
                                               const float* __restrict__ gamma,
                                               const float* __restrict__ beta,
                                               float* __restrict__ scale,
                                               float* __restrict__ shift, int M) {
    int c = threadIdx.x;
    float inv = 1.0f / (float)M;
    float mean = bnsum[c] * inv;
    float var = bnss[c] * inv - mean * mean;
    if (var < 0.f) var = 0.f;
    float rstd = rsqrtf(var + 1e-5f);
    float sc = rstd * gamma[c];
    scale[c] = sc;
    shift[c] = beta[c] - mean * sc;
}

// ---------------- mm2: out = relu(norm(h1)) @ W2 (norm fused in A-stage) ----------------

__global__ __launch_bounds__(256) void k_mm2(const u16* __restrict__ H1,
                                             const float* __restrict__ scale,
                                             const float* __restrict__ shift,
                                             const u16* __restrict__ WT,
                                             float* __restrict__ outf,
                                             u16* __restrict__ outb, int M) {
    __shared__ u16 As[128][72];
    __shared__ u16 Bs[128][72];
    int row0 = blockIdx.x * 128;
    int tid = threadIdx.x;
    int lane = tid & 63, w = tid >> 6;
    int r0w = (w & 1) * 64, c0w = (w >> 1) * 64;
    int q = lane >> 4, ml = lane & 15;

    f32x4 acc[4][4];
    #pragma unroll
    for (int i = 0; i < 4; ++i)
        #pragma unroll
        for (int j = 0; j < 4; ++j) acc[i][j] = f32x4{0.f, 0.f, 0.f, 0.f};

    for (int kk = 0; kk < 256; kk += 64) {
        #pragma unroll
        for (int i = 0; i < 4; ++i) {
            int r = i * 32 + (tid >> 3);
            int c8 = (tid & 7) * 8;
            s16x8 o = s16x8{0, 0, 0, 0, 0, 0, 0, 0};
            if (row0 + r < M) {
                s16x8 v = *reinterpret_cast<const s16x8*>(&H1[(size_t)(row0 + r) * H + kk + c8]);
                #pragma unroll
                for (int j = 0; j < 8; ++j) {
                    float f = b2f((u16)v[j]) * scale[kk + c8 + j] + shift[kk + c8 + j];
                    o[j] = (short)f2b(fmaxf(f, 0.f));
                }
            }
            *reinterpret_cast<s16x8*>(&As[r][c8]) = o;
            s16x8 vb = *reinterpret_cast<const s16x8*>(&WT[(size_t)r * H + kk + c8]);
            *reinterpret_cast<s16x8*>(&Bs[r][c8]) = vb;
        }
        __syncthreads();
        #pragma unroll
        for (int ks = 0; ks < 64; ks += 32) {
            s16x8 af[4], bfr[4];
            #pragma unroll
            for (int rt = 0; rt < 4; ++rt)
                af[rt] = *reinterpret_cast<const s16x8*>(&As[r0w + rt * 16 + ml][ks + q * 8]);
            #pragma unroll
            for (int ct = 0; ct < 4; ++ct)
                bfr[ct] = *reinterpret_cast<const s16x8*>(&Bs[c0w + ct * 16 + ml][ks + q * 8]);
            #pragma unroll
            for (int rt = 0; rt < 4; ++rt)
                #pragma unroll
                for (int ct = 0; ct < 4; ++ct)
                    acc[rt][ct] = __builtin_amdgcn_mfma_f32_16x16x32_bf16(
                        af[rt], bfr[ct], acc[rt][ct], 0, 0, 0);
        }
        __syncthreads();
    }

    #pragma unroll
    for (int ct = 0; ct < 4; ++ct) {
        int col = c0w + ct * 16 + ml;
        #pragma unroll
        for (int rt = 0; rt < 4; ++rt) {
            int rbase = row0 + r0w + rt * 16 + q * 4;
            #pragma unroll
            for (int rg = 0; rg < 4; ++rg) {
                if (rbase + rg < M) {
                    float v = acc[rt][ct][rg];
                    if (outb)
                        outb[(size_t)(rbase + rg) * D + col] = f2b(fmaxf(v, 0.f));
                    else
                        outf[(size_t)(rbase + rg) * D + col] = v;
                }
            }
        }
    }
}

// ---------------- host launch ----------------

extern "C" void kernel_launch(void* const* d_in, const int* in_sizes, int n_in,
                              void* d_out, int out_size, void* d_ws, size_t ws_size,
                              hipStream_t stream) {
    const float* x         = (const float*)d_in[0];
    const int*   ei        = (const int*)d_in[1];
    const float* t_all     = (const float*)d_in[2];
    const float* W1_all    = (const float*)d_in[3];
    const float* W2_all    = (const float*)d_in[4];
    const float* gamma_all = (const float*)d_in[5];
    const float* beta_all  = (const float*)d_in[6];

    int N = in_sizes[0] / D;
    int E = in_sizes[1] / 2;
    float* out = (float*)d_out;

    char* ws = (char*)d_ws;
    size_t off = 0;
    auto alloc = [&](size_t bytes) -> void* {
        void* p = ws + off;
        off += (bytes + 255) & ~(size_t)255;
        return p;
    };
    int B = (N + 1023) >> 10;   // scan blocks
    int* rowptr = (int*)alloc((size_t)(N + 1) * 4);
    int* deg    = (int*)alloc((size_t)N * 4);
    int* srcs   = (int*)alloc((size_t)E * 4);
    int* bsum   = (int*)alloc((size_t)(B + 1) * 4);
    u16* xb     = (u16*)alloc((size_t)N * D * 2);
    u16* a0     = (u16*)alloc((size_t)N * D * 2);
    u16* a1     = (u16*)alloc((size_t)N * D * 2);
    u16* g      = (u16*)alloc((size_t)N * D * 2);
    u16* h1     = (u16*)alloc((size_t)N * H * 2);
    u16* WT1    = (u16*)alloc((size_t)4 * H * D * 2);
    u16* WT2    = (u16*)alloc((size_t)4 * D * H * 2);
    float* bnsum = (float*)alloc(H * 4);
    float* bnss  = (float*)alloc(H * 4);
    float* scale = (float*)alloc(H * 4);
    float* shift = (float*)alloc(H * 4);
    (void)ws_size; (void)n_in; (void)out_size;

    const int* srcA = ei;
    const int* dstA = ei + E;

    // prep: bf16 casts + weight transposes
    k_cvt<<<(N * D / 4 + 255) / 256, 256, 0, stream>>>(x, xb, N * D / 4);
    k_prep<<<1024, 256, 0, stream>>>(W1_all, W2_all, WT1, WT2);

    // CSR build (hierarchical 3-phase scan)
    hipMemsetAsync(deg, 0, (size_t)N * 4, stream);
    k_count<<<(E + 255) / 256, 256, 0, stream>>>(dstA, deg, E);
    k_scan1<<<B, 1024, 0, stream>>>(deg, rowptr, bsum, N);
    k_scan2<<<1, 1024, 0, stream>>>(bsum, B);
    k_scan3<<<(N + 1 + 1023) / 1024, 1024, 0, stream>>>(rowptr, bsum, N, E);
    hipMemsetAsync(deg, 0, (size_t)N * 4, stream);
    k_scatter<<<(E + 255) / 256, 256, 0, stream>>>(srcA, dstA, rowptr, deg, srcs, E);

    float* out0 = out;                  // mu
    float* out1 = out + (size_t)N * D;  // logstd

    int gx = (N + 127) / 128;
    for (int layer = 0; layer < 4; ++layer) {
        const u16* hin = (layer == 0) ? xb : (layer == 1 ? a0 : a1);
        k_edge<<<(N + 3) / 4, 256, 0, stream>>>(hin, rowptr, srcs, t_all + layer,
                                                g, bnsum, bnss, N);

        k_mm1<<<dim3(gx, 2), 256, 0, stream>>>(g, WT1 + (size_t)layer * H * D, h1,
                                               bnsum, bnss, N);
        k_bnfin<<<1, H, 0, stream>>>(bnsum, bnss, gamma_all + (size_t)layer * H,
                                     beta_all + (size_t)layer * H, scale, shift, N);

        float* outf = nullptr;
        u16*   outb = nullptr;
        if (layer == 0)      outb = a0;
        else if (layer == 1) outb = a1;
        else if (layer == 2) outf = out0;
        else                 outf = out1;

        k_mm2<<<dim3(gx, 1), 256, 0, stream>>>(h1, scale, shift,
                                               WT2 + (size_t)layer * D * H,
                                               outf, outb, N);
    }
}

// Round 5
// 800.125 us; speedup vs baseline: 1.3657x; 1.1658x over previous
//
#include <hip/hip_runtime.h>
#include <math.h>

#define D 128
#define H 256
#define NSLOT 64   // BN partial-sum slot copies (kills atomic contention)

typedef short s16x8 __attribute__((ext_vector_type(8)));  // 8 bf16 bit-patterns (4 VGPRs)
typedef float f32x4 __attribute__((ext_vector_type(4)));
typedef unsigned int u32x2 __attribute__((ext_vector_type(2)));
typedef unsigned short u16;
typedef unsigned int u32;

// float -> bf16 (round-nearest-even) as bit pattern
__device__ __forceinline__ u16 f2b(float f) {
    union { float f; unsigned u; } c;
    c.f = f;
    unsigned u = c.u + 0x7FFFu + ((c.u >> 16) & 1u);
    return (u16)(u >> 16);
}
__device__ __forceinline__ float b2f(u16 h) {
    union { unsigned u; float f; } c;
    c.u = ((unsigned)h) << 16;
    return c.f;
}
__device__ __forceinline__ float blo(u32 p) {   // bf16 in low half
    union { unsigned u; float f; } c;
    c.u = p << 16;
    return c.f;
}
__device__ __forceinline__ float bhi(u32 p) {   // bf16 in high half
    union { unsigned u; float f; } c;
    c.u = p & 0xFFFF0000u;
    return c.f;
}

// ---------------- CSR build ----------------

__global__ __launch_bounds__(256) void k_count(const int* __restrict__ dstA,
                                               int* __restrict__ deg, int E) {
    int e = blockIdx.x * 256 + threadIdx.x;
    if (e < E) atomicAdd(&deg[dstA[e]], 1);
}

// 3-phase hierarchical exclusive scan.
__global__ __launch_bounds__(1024) void k_scan1(const int* __restrict__ deg,
                                                int* __restrict__ rowptr,
                                                int* __restrict__ bsum, int N) {
    __shared__ int tmp[1024];
    int t = threadIdx.x;
    int i = blockIdx.x * 1024 + t;
    int v = (i < N) ? deg[i] : 0;
    tmp[t] = v;
    __syncthreads();
    #pragma unroll
    for (int off = 1; off < 1024; off <<= 1) {
        int u = (t >= off) ? tmp[t - off] : 0;
        __syncthreads();
        tmp[t] += u;
        __syncthreads();
    }
    if (i < N) rowptr[i] = tmp[t] - v;      // exclusive within block
    if (t == 1023) bsum[blockIdx.x] = tmp[1023];
}

__global__ __launch_bounds__(1024) void k_scan2(int* __restrict__ bsum, int B) {
    __shared__ int sums[1024];
    int t = threadIdx.x;
    int chunk = (B + 1023) >> 10;
    int beg = t * chunk;
    int end = beg + chunk;
    if (end > B) end = B;
    int s = 0;
    for (int i = beg; i < end; ++i) s += bsum[i];
    sums[t] = s;
    __syncthreads();
    #pragma unroll
    for (int off = 1; off < 1024; off <<= 1) {
        int v = (t >= off) ? sums[t - off] : 0;
        __syncthreads();
        sums[t] += v;
        __syncthreads();
    }
    int run = (t == 0) ? 0 : sums[t - 1];
    for (int i = beg; i < end; ++i) {
        int v = bsum[i];
        bsum[i] = run;
        run += v;
    }
}

__global__ __launch_bounds__(1024) void k_scan3(int* __restrict__ rowptr,
                                                const int* __restrict__ bsum,
                                                int N, int E) {
    int i = blockIdx.x * 1024 + threadIdx.x;
    if (i < N) rowptr[i] += bsum[blockIdx.x];
    else if (i == N) rowptr[N] = E;
}

__global__ __launch_bounds__(256) void k_scatter(const int* __restrict__ srcA,
                                                 const int* __restrict__ dstA,
                                                 const int* __restrict__ rowptr,
                                                 int* __restrict__ cnt,
                                                 int* __restrict__ srcs, int E) {
    int e = blockIdx.x * 256 + threadIdx.x;
    if (e < E) {
        int d = dstA[e];
        int p = rowptr[d] + atomicAdd(&cnt[d], 1);
        srcs[p] = srcA[e];
    }
}

// ---------------- prep: fp32 -> bf16 casts & weight transpose ----------------

__global__ __launch_bounds__(256) void k_cvt(const float* __restrict__ x,
                                             u16* __restrict__ xb, int n4) {
    int i = blockIdx.x * 256 + threadIdx.x;
    if (i < n4) {
        float4 v = ((const float4*)x)[i];
        xb[i * 4 + 0] = f2b(v.x);
        xb[i * 4 + 1] = f2b(v.y);
        xb[i * 4 + 2] = f2b(v.z);
        xb[i * 4 + 3] = f2b(v.w);
    }
}

// WT1[l][n(256)][k(128)] = W1[l][k][n];  WT2[l][n(128)][k(256)] = W2[l][k][n]
__global__ __launch_bounds__(256) void k_prep(const float* __restrict__ W1_all,
                                              const float* __restrict__ W2_all,
                                              u16* __restrict__ WT1,
                                              u16* __restrict__ WT2) {
    int id = blockIdx.x * 256 + threadIdx.x;   // 262144 total
    if (id < 131072) {
        int l = id >> 15, rem = id & 32767, n = rem >> 7, k = rem & 127;
        WT1[id] = f2b(W1_all[l * 32768 + k * 256 + n]);
    } else {
        int id2 = id - 131072;
        int l = id2 >> 15, rem = id2 & 32767, n = rem >> 8, k = rem & 255;
        WT2[id2] = f2b(W2_all[l * 32768 + k * 128 + n]);
    }
}

// ---------------- edge softmax-aggregation ----------------
// v4 structure (1 node/wave, readlane-scalarized gathers, 16-deep pipeline).
// Blocks 0..NSLOT-1 zero the BN partial-slot buffers for this layer's mm1.

__global__ __launch_bounds__(256) void k_edge(const u16* __restrict__ hin,
                                              const int* __restrict__ rowptr,
                                              const int* __restrict__ srcs,
                                              const float* __restrict__ tptr,
                                              u16* __restrict__ g,
                                              float* __restrict__ psum,
                                              float* __restrict__ pss, int N) {
    if (blockIdx.x < NSLOT) {    // zero BN partial slots for this layer's mm1
        psum[blockIdx.x * 256 + threadIdx.x] = 0.f;
        pss[blockIdx.x * 256 + threadIdx.x] = 0.f;
    }
    int u = blockIdx.x * 4 + (threadIdx.x >> 6);
    if (u >= N) return;
    u = __builtin_amdgcn_readfirstlane(u);   // wave-uniform -> SGPR
    int lane = threadIdx.x & 63;
    const u32* hin32 = (const u32*)hin;
    float t = *tptr;
    int beg = rowptr[u], end = rowptr[u + 1];   // scalar loads
    int cnt = end - beg;

    // own row: independent load, issued before the gather loop
    u32 pu = hin32[(size_t)u * 64 + lane];

    float s0 = 0.f, s1 = 0.f, sn0 = 0.f, sn1 = 0.f;
    float mx = -3.0e38f, mv = 0.f;

    for (int b = 0; b < cnt; b += 64) {
        int nb = cnt - b;
        if (nb > 64) nb = 64;
        // one coalesced load: lane l holds src index of edge (b+l)
        int sv = (b + lane < cnt) ? srcs[beg + b + lane] : 0;
        for (int ib = 0; ib < nb; ib += 16) {
            int m = nb - ib;
            if (m > 16) m = 16;
            u32 pr[16];
            #pragma unroll
            for (int j = 0; j < 16; ++j) {
                if (j < m) {
                    // uniform broadcast -> SGPR index -> scalar base address
                    int vi = __builtin_amdgcn_readlane(sv, ib + j);
                    pr[j] = hin32[(size_t)vi * 64 + lane];
                }
            }
            #pragma unroll
            for (int j = 0; j < 16; ++j) {
                if (j < m) {
                    u32 p = pr[j];
                    float v0 = fmaxf(blo(p), 0.f) + 1e-7f;
                    float v1 = fmaxf(bhi(p), 0.f) + 1e-7f;
                    float l0 = v0 * t, l1 = v1 * t;
                    mx = fmaxf(mx, fmaxf(l0, l1));
                    mv = fmaxf(mv, fmaxf(v0, v1));
                    float w0 = __expf(l0), w1 = __expf(l1);
                    s0 += w0; s1 += w1;
                    sn0 = fmaf(w0, v0, sn0);
                    sn1 = fmaf(w1, v1, sn1);
                }
            }
        }
    }

    bool has = (cnt > 0);
    if (__any(has && (mx > 60.f || mx < -20.f || mv > 1.0e10f))) {
        // exact online-softmax fallback (rare; correct for any t / magnitudes)
        float m0 = -3.0e38f, m1 = -3.0e38f;
        s0 = s1 = sn0 = sn1 = 0.f;
        for (int e = beg; e < end; ++e) {
            int v = srcs[e];
            u32 p = hin32[(size_t)v * 64 + lane];
            float v0 = fmaxf(blo(p), 0.f) + 1e-7f;
            float v1 = fmaxf(bhi(p), 0.f) + 1e-7f;
            float l0 = v0 * t, l1 = v1 * t;
            float nm0 = fmaxf(m0, l0), nm1 = fmaxf(m1, l1);
            float a0 = __expf(m0 - nm0), a1 = __expf(m1 - nm1);
            float w0 = __expf(l0 - nm0), w1 = __expf(l1 - nm1);
            s0 = s0 * a0 + w0;           s1 = s1 * a1 + w1;
            sn0 = sn0 * a0 + w0 * v0;    sn1 = sn1 * a1 + w1 * v1;
            m0 = nm0; m1 = nm1;
        }
    }

    float aggr0 = sn0 / (s0 + 1e-16f);
    float aggr1 = sn1 / (s1 + 1e-16f);
    float o0 = aggr0 + blo(pu);
    float o1 = aggr1 + bhi(pu);
    ((u32*)g)[(size_t)u * 64 + lane] = (u32)f2b(o0) | ((u32)f2b(o1) << 16);
}

// ---------------- mm1: h1 = g @ W1 (bf16 MFMA), fused BN partials ----------------
// 128x128 tile, 256 threads (4 waves), BK=64, K=128.
// v5: operand-swapped MFMA (bfr, af) -> lane holds C[row=ml][4 consecutive cols]
//     => 16x 8B vector C-stores per thread (was 64x 2B scatters).
//     BN partials via shfl_xor butterfly over ml-lanes (no LDS atomics) and
//     one atomicAdd per col into NSLOT slot copies (was 1564 blocks x same line).

__global__ __launch_bounds__(256) void k_mm1(const u16* __restrict__ A,
                                             const u16* __restrict__ WT,
                                             u16* __restrict__ C,
                                             float* __restrict__ psum,
                                             float* __restrict__ pss, int M) {
    __shared__ u16 As[128][72];   // stride 144B: 2-way bank alias (free)
    __shared__ u16 Bs[128][72];
    __shared__ float csumA[128], cssA[128], csumB[128], cssB[128];
    int row0 = blockIdx.x * 128, n0 = blockIdx.y * 128;
    int tid = threadIdx.x;
    int lane = tid & 63, w = tid >> 6;
    int r0w = (w & 1) * 64, c0w = (w >> 1) * 64;
    int q = lane >> 4, ml = lane & 15;

    f32x4 acc[4][4];
    #pragma unroll
    for (int i = 0; i < 4; ++i)
        #pragma unroll
        for (int j = 0; j < 4; ++j) acc[i][j] = f32x4{0.f, 0.f, 0.f, 0.f};

    for (int kk = 0; kk < 128; kk += 64) {
        #pragma unroll
        for (int i = 0; i < 4; ++i) {
            int r = i * 32 + (tid >> 3);
            int c8 = (tid & 7) * 8;
            s16x8 va = s16x8{0, 0, 0, 0, 0, 0, 0, 0};
            if (row0 + r < M)
                va = *reinterpret_cast<const s16x8*>(&A[(size_t)(row0 + r) * 128 + kk + c8]);
            *reinterpret_cast<s16x8*>(&As[r][c8]) = va;
            s16x8 vb = *reinterpret_cast<const s16x8*>(&WT[(size_t)(n0 + r) * 128 + kk + c8]);
            *reinterpret_cast<s16x8*>(&Bs[r][c8]) = vb;
        }
        __syncthreads();
        #pragma unroll
        for (int ks = 0; ks < 64; ks += 32) {
            s16x8 af[4], bfr[4];
            #pragma unroll
            for (int rt = 0; rt < 4; ++rt)
                af[rt] = *reinterpret_cast<const s16x8*>(&As[r0w + rt * 16 + ml][ks + q * 8]);
            #pragma unroll
            for (int ct = 0; ct < 4; ++ct)
                bfr[ct] = *reinterpret_cast<const s16x8*>(&Bs[c0w + ct * 16 + ml][ks + q * 8]);
            #pragma unroll
            for (int rt = 0; rt < 4; ++rt)
                #pragma unroll
                for (int ct = 0; ct < 4; ++ct)
                    acc[rt][ct] = __builtin_amdgcn_mfma_f32_16x16x32_bf16(
                        bfr[ct], af[rt], acc[rt][ct], 0, 0, 0);  // swapped!
        }
        __syncthreads();
    }

    // ---- C stores: lane (q,ml) holds C[r0w+rt*16+ml][c0w+ct*16+q*4 .. +3] ----
    #pragma unroll
    for (int rt = 0; rt < 4; ++rt) {
        int row = row0 + r0w + rt * 16 + ml;
        if (row < M) {
            #pragma unroll
            for (int ct = 0; ct < 4; ++ct) {
                f32x4 a = acc[rt][ct];
                u32x2 p;
                p.x = (u32)f2b(a[0]) | ((u32)f2b(a[1]) << 16);
                p.y = (u32)f2b(a[2]) | ((u32)f2b(a[3]) << 16);
                int col = n0 + c0w + ct * 16 + q * 4;
                *reinterpret_cast<u32x2*>(&C[(size_t)row * H + col]) = p;
            }
        }
    }

    // ---- BN partials: per-lane col sums over its 4 rt-rows, butterfly over ml ----
    float sp[16], ssp[16];
    #pragma unroll
    for (int ct = 0; ct < 4; ++ct)
        #pragma unroll
        for (int r = 0; r < 4; ++r) {
            float s = 0.f, ss = 0.f;
            #pragma unroll
            for (int rt = 0; rt < 4; ++rt) {
                float v = acc[rt][ct][r];   // OOB rows staged as 0 -> contribute 0
                s += v;
                ss += v * v;
            }
            sp[ct * 4 + r] = s;
            ssp[ct * 4 + r] = ss;
        }
    #pragma unroll
    for (int msk = 1; msk < 16; msk <<= 1) {
        #pragma unroll
        for (int i = 0; i < 16; ++i) {
            sp[i] += __shfl_xor(sp[i], msk);
            ssp[i] += __shfl_xor(ssp[i], msk);
        }
    }
    if (ml == 0) {   // q-group leader: holds sums over this wave's 64 rows
        float* cs = (w & 1) ? csumB : csumA;
        float* cq = (w & 1) ? cssB : cssA;
        #pragma unroll
        for (int ct = 0; ct < 4; ++ct)
            #pragma unroll
            for (int r = 0; r < 4; ++r) {
                int col = c0w + ct * 16 + q * 4 + r;
                cs[col] = sp[ct * 4 + r];
                cq[col] = ssp[ct * 4 + r];
            }
    }
    __syncthreads();
    if (tid < 128) {
        int slot = blockIdx.x & (NSLOT - 1);
        atomicAdd(&psum[(size_t)slot * 256 + n0 + tid], csumA[tid] + csumB[tid]);
        atomicAdd(&pss[(size_t)slot * 256 + n0 + tid], cssA[tid] + cssB[tid]);
    }
}

// ---------------- BN finalize (reduce NSLOT slot copies) ----------------

__global__ __launch_bounds__(256) void k_bnfin(const float* __restrict__ psum,
                                               const float* __restrict__ pss,
                                               const float* __restrict__ gamma,
                                               const float* __restrict__ beta,
                                               float* __restrict__ scale,
                                               float* __restrict__ shift, int M) {
    int c = threadIdx.x;
    float s = 0.f, ss = 0.f;
    for (int b = 0; b < NSLOT; ++b) {
        s += psum[b * 256 + c];
        ss += pss[b * 256 + c];
    }
    float inv = 1.0f / (float)M;
    float mean = s * inv;
    float var = ss * inv - mean * mean;
    if (var < 0.f) var = 0.f;
    float rstd = rsqrtf(var + 1e-5f);
    float sc = rstd * gamma[c];
    scale[c] = sc;
    shift[c] = beta[c] - mean * sc;
}

// ---------------- mm2: out = relu(norm(h1)) @ W2 (norm fused in A-stage) ----------------
// v5: operand-swapped MFMA -> fp32 out = fully-coalesced float4 stores
//     (full 64B lines per instruction), bf16 out = 8B vector stores.

__global__ __launch_bounds__(256) void k_mm2(const u16* __restrict__ H1,
                                             const float* __restrict__ scale,
                                             const float* __restrict__ shift,
                                             const u16* __restrict__ WT,
                                             float* __restrict__ outf,
                                             u16* __restrict__ outb, int M) {
    __shared__ u16 As[128][72];
    __shared__ u16 Bs[128][72];
    int row0 = blockIdx.x * 128;
    int tid = threadIdx.x;
    int lane = tid & 63, w = tid >> 6;
    int r0w = (w & 1) * 64, c0w = (w >> 1) * 64;
    int q = lane >> 4, ml = lane & 15;

    f32x4 acc[4][4];
    #pragma unroll
    for (int i = 0; i < 4; ++i)
        #pragma unroll
        for (int j = 0; j < 4; ++j) acc[i][j] = f32x4{0.f, 0.f, 0.f, 0.f};

    for (int kk = 0; kk < 256; kk += 64) {
        #pragma unroll
        for (int i = 0; i < 4; ++i) {
            int r = i * 32 + (tid >> 3);
            int c8 = (tid & 7) * 8;
            s16x8 o = s16x8{0, 0, 0, 0, 0, 0, 0, 0};
            if (row0 + r < M) {
                s16x8 v = *reinterpret_cast<const s16x8*>(&H1[(size_t)(row0 + r) * H + kk + c8]);
                #pragma unroll
                for (int j = 0; j < 8; ++j) {
                    float f = b2f((u16)v[j]) * scale[kk + c8 + j] + shift[kk + c8 + j];
                    o[j] = (short)f2b(fmaxf(f, 0.f));
                }
            }
            *reinterpret_cast<s16x8*>(&As[r][c8]) = o;
            s16x8 vb = *reinterpret_cast<const s16x8*>(&WT[(size_t)r * H + kk + c8]);
            *reinterpret_cast<s16x8*>(&Bs[r][c8]) = vb;
        }
        __syncthreads();
        #pragma unroll
        for (int ks = 0; ks < 64; ks += 32) {
            s16x8 af[4], bfr[4];
            #pragma unroll
            for (int rt = 0; rt < 4; ++rt)
                af[rt] = *reinterpret_cast<const s16x8*>(&As[r0w + rt * 16 + ml][ks + q * 8]);
            #pragma unroll
            for (int ct = 0; ct < 4; ++ct)
                bfr[ct] = *reinterpret_cast<const s16x8*>(&Bs[c0w + ct * 16 + ml][ks + q * 8]);
            #pragma unroll
            for (int rt = 0; rt < 4; ++rt)
                #pragma unroll
                for (int ct = 0; ct < 4; ++ct)
                    acc[rt][ct] = __builtin_amdgcn_mfma_f32_16x16x32_bf16(
                        bfr[ct], af[rt], acc[rt][ct], 0, 0, 0);  // swapped!
        }
        __syncthreads();
    }

    #pragma unroll
    for (int rt = 0; rt < 4; ++rt) {
        int row = row0 + r0w + rt * 16 + ml;
        if (row < M) {
            #pragma unroll
            for (int ct = 0; ct < 4; ++ct) {
                f32x4 a = acc[rt][ct];
                int col = c0w + ct * 16 + q * 4;
                if (outb) {
                    u32x2 p;
                    p.x = (u32)f2b(fmaxf(a[0], 0.f)) | ((u32)f2b(fmaxf(a[1], 0.f)) << 16);
                    p.y = (u32)f2b(fmaxf(a[2], 0.f)) | ((u32)f2b(fmaxf(a[3], 0.f)) << 16);
                    *reinterpret_cast<u32x2*>(&outb[(size_t)row * D + col]) = p;
                } else {
                    *reinterpret_cast<f32x4*>(&outf[(size_t)row * D + col]) = a;
                }
            }
        }
    }
}

// ---------------- host launch ----------------

extern "C" void kernel_launch(void* const* d_in, const int* in_sizes, int n_in,
                              void* d_out, int out_size, void* d_ws, size_t ws_size,
                              hipStream_t stream) {
    const float* x         = (const float*)d_in[0];
    const int*   ei        = (const int*)d_in[1];
    const float* t_all     = (const float*)d_in[2];
    const float* W1_all    = (const float*)d_in[3];
    const float* W2_all    = (const float*)d_in[4];
    const float* gamma_all = (const float*)d_in[5];
    const float* beta_all  = (const float*)d_in[6];

    int N = in_sizes[0] / D;
    int E = in_sizes[1] / 2;
    float* out = (float*)d_out;

    char* ws = (char*)d_ws;
    size_t off = 0;
    auto alloc = [&](size_t bytes) -> void* {
        void* p = ws + off;
        off += (bytes + 255) & ~(size_t)255;
        return p;
    };
    int B = (N + 1023) >> 10;   // scan blocks
    int* rowptr = (int*)alloc((size_t)(N + 1) * 4);
    int* deg    = (int*)alloc((size_t)N * 4);
    int* srcs   = (int*)alloc((size_t)E * 4);
    int* bsum   = (int*)alloc((size_t)(B + 1) * 4);
    u16* xb     = (u16*)alloc((size_t)N * D * 2);
    u16* a0     = (u16*)alloc((size_t)N * D * 2);
    u16* a1     = (u16*)alloc((size_t)N * D * 2);
    u16* g      = (u16*)alloc((size_t)N * D * 2);
    u16* h1     = (u16*)alloc((size_t)N * H * 2);
    u16* WT1    = (u16*)alloc((size_t)4 * H * D * 2);
    u16* WT2    = (u16*)alloc((size_t)4 * D * H * 2);
    float* psum = (float*)alloc((size_t)NSLOT * 256 * 4);
    float* pss  = (float*)alloc((size_t)NSLOT * 256 * 4);
    float* scale = (float*)alloc(H * 4);
    float* shift = (float*)alloc(H * 4);
    (void)ws_size; (void)n_in; (void)out_size;

    const int* srcA = ei;
    const int* dstA = ei + E;

    // prep: bf16 casts + weight transposes
    k_cvt<<<(N * D / 4 + 255) / 256, 256, 0, stream>>>(x, xb, N * D / 4);
    k_prep<<<1024, 256, 0, stream>>>(W1_all, W2_all, WT1, WT2);

    // CSR build (hierarchical 3-phase scan)
    hipMemsetAsync(deg, 0, (size_t)N * 4, stream);
    k_count<<<(E + 255) / 256, 256, 0, stream>>>(dstA, deg, E);
    k_scan1<<<B, 1024, 0, stream>>>(deg, rowptr, bsum, N);
    k_scan2<<<1, 1024, 0, stream>>>(bsum, B);
    k_scan3<<<(N + 1 + 1023) / 1024, 1024, 0, stream>>>(rowptr, bsum, N, E);
    hipMemsetAsync(deg, 0, (size_t)N * 4, stream);
    k_scatter<<<(E + 255) / 256, 256, 0, stream>>>(srcA, dstA, rowptr, deg, srcs, E);

    float* out0 = out;                  // mu
    float* out1 = out + (size_t)N * D;  // logstd

    int gx = (N + 127) / 128;
    for (int layer = 0; layer < 4; ++layer) {
        const u16* hin = (layer == 0) ? xb : (layer == 1 ? a0 : a1);
        k_edge<<<(N + 3) / 4, 256, 0, stream>>>(hin, rowptr, srcs, t_all + layer,
                                                g, psum, pss, N);

        k_mm1<<<dim3(gx, 2), 256, 0, stream>>>(g, WT1 + (size_t)layer * H * D, h1,
                                               psum, pss, N);
        k_bnfin<<<1, H, 0, stream>>>(psum, pss, gamma_all + (size_t)layer * H,
                                     beta_all + (size_t)layer * H, scale, shift, N);

        float* outf = nullptr;
        u16*   outb = nullptr;
        if (layer == 0)      outb = a0;
        else if (layer == 1) outb = a1;
        else if (layer == 2) outf = out0;
        else                 outf = out1;

        k_mm2<<<dim3(gx, 1), 256, 0, stream>>>(h1, scale, shift,
                                               WT2 + (size_t)layer * D * H,
                                               outf, outb, N);
    }
}

// Round 6
// 797.575 us; speedup vs baseline: 1.3700x; 1.0032x over previous
//
#include <hip/hip_runtime.h>
#include <math.h>

#define D 128
#define H 256
#define NSLOT 64   // BN partial-sum slot copies (kills atomic contention)

typedef short s16x8 __attribute__((ext_vector_type(8)));  // 8 bf16 bit-patterns (4 VGPRs)
typedef float f32x4 __attribute__((ext_vector_type(4)));
typedef unsigned int u32x2 __attribute__((ext_vector_type(2)));
typedef unsigned short u16;
typedef unsigned int u32;

// float -> bf16 (round-nearest-even) as bit pattern
__device__ __forceinline__ u16 f2b(float f) {
    union { float f; unsigned u; } c;
    c.f = f;
    unsigned u = c.u + 0x7FFFu + ((c.u >> 16) & 1u);
    return (u16)(u >> 16);
}
__device__ __forceinline__ float b2f(u16 h) {
    union { unsigned u; float f; } c;
    c.u = ((unsigned)h) << 16;
    return c.f;
}
__device__ __forceinline__ float blo(u32 p) {   // bf16 in low half
    union { unsigned u; float f; } c;
    c.u = p << 16;
    return c.f;
}
__device__ __forceinline__ float bhi(u32 p) {   // bf16 in high half
    union { unsigned u; float f; } c;
    c.u = p & 0xFFFF0000u;
    return c.f;
}

// ---------------- CSR build ----------------

__global__ __launch_bounds__(256) void k_count(const int* __restrict__ dstA,
                                               int* __restrict__ deg, int E) {
    int e = blockIdx.x * 256 + threadIdx.x;
    if (e < E) atomicAdd(&deg[dstA[e]], 1);
}

// 3-phase hierarchical exclusive scan.
__global__ __launch_bounds__(1024) void k_scan1(const int* __restrict__ deg,
                                                int* __restrict__ rowptr,
                                                int* __restrict__ bsum, int N) {
    __shared__ int tmp[1024];
    int t = threadIdx.x;
    int i = blockIdx.x * 1024 + t;
    int v = (i < N) ? deg[i] : 0;
    tmp[t] = v;
    __syncthreads();
    #pragma unroll
    for (int off = 1; off < 1024; off <<= 1) {
        int u = (t >= off) ? tmp[t - off] : 0;
        __syncthreads();
        tmp[t] += u;
        __syncthreads();
    }
    if (i < N) rowptr[i] = tmp[t] - v;      // exclusive within block
    if (t == 1023) bsum[blockIdx.x] = tmp[1023];
}

__global__ __launch_bounds__(1024) void k_scan2(int* __restrict__ bsum, int B) {
    __shared__ int sums[1024];
    int t = threadIdx.x;
    int chunk = (B + 1023) >> 10;
    int beg = t * chunk;
    int end = beg + chunk;
    if (end > B) end = B;
    int s = 0;
    for (int i = beg; i < end; ++i) s += bsum[i];
    sums[t] = s;
    __syncthreads();
    #pragma unroll
    for (int off = 1; off < 1024; off <<= 1) {
        int v = (t >= off) ? sums[t - off] : 0;
        __syncthreads();
        sums[t] += v;
        __syncthreads();
    }
    int run = (t == 0) ? 0 : sums[t - 1];
    for (int i = beg; i < end; ++i) {
        int v = bsum[i];
        bsum[i] = run;
        run += v;
    }
}

// Phase 3: finalize rowptr, write rowptr[N]=E, and re-zero deg (scatter counter).
__global__ __launch_bounds__(1024) void k_scan3(int* __restrict__ rowptr,
                                                const int* __restrict__ bsum,
                                                int* __restrict__ deg,
                                                int N, int E) {
    int i = blockIdx.x * 1024 + threadIdx.x;
    if (i < N) {
        rowptr[i] += bsum[blockIdx.x];
        deg[i] = 0;
    } else if (i == N) {
        rowptr[N] = E;
    }
}

__global__ __launch_bounds__(256) void k_scatter(const int* __restrict__ srcA,
                                                 const int* __restrict__ dstA,
                                                 const int* __restrict__ rowptr,
                                                 int* __restrict__ cnt,
                                                 int* __restrict__ srcs, int E) {
    int e = blockIdx.x * 256 + threadIdx.x;
    if (e < E) {
        int d = dstA[e];
        int p = rowptr[d] + atomicAdd(&cnt[d], 1);
        srcs[p] = srcA[e];
    }
}

// ---------------- prep: fused bf16 cast + weight transpose + deg zero ----------------
// id < n4            : x -> xb (float4 -> 4x bf16)
// id - n4 < 131072   : WT1[l][n][k] = W1[l][k][n]
// next 131072        : WT2[l][n][k] = W2[l][k][n]
// id < N             : deg[id] = 0 (saves a memset dispatch)

__global__ __launch_bounds__(256) void k_cvtprep(const float* __restrict__ x,
                                                 u16* __restrict__ xb,
                                                 const float* __restrict__ W1_all,
                                                 const float* __restrict__ W2_all,
                                                 u16* __restrict__ WT1,
                                                 u16* __restrict__ WT2,
                                                 int* __restrict__ deg,
                                                 int n4, int N) {
    int id = blockIdx.x * 256 + threadIdx.x;
    if (id < N) deg[id] = 0;
    if (id < n4) {
        float4 v = ((const float4*)x)[id];
        xb[id * 4 + 0] = f2b(v.x);
        xb[id * 4 + 1] = f2b(v.y);
        xb[id * 4 + 2] = f2b(v.z);
        xb[id * 4 + 3] = f2b(v.w);
    } else {
        int p = id - n4;
        if (p < 131072) {
            int l = p >> 15, rem = p & 32767, n = rem >> 7, k = rem & 127;
            WT1[p] = f2b(W1_all[l * 32768 + k * 256 + n]);
        } else if (p < 262144) {
            int p2 = p - 131072;
            int l = p2 >> 15, rem = p2 & 32767, n = rem >> 8, k = rem & 255;
            WT2[p2] = f2b(W2_all[l * 32768 + k * 128 + n]);
        }
    }
}

// ---------------- edge softmax-aggregation ----------------
// v6: v4 structure (1 node/wave, readlane-scalarized gathers, 16-deep pipeline)
// minus the per-edge mx/mv fmax chains: the exact-online fallback is now
// triggered by a POST-HOC range/finiteness check on the sums (overflow -> inf
// or s>1e26 caught; total underflow -> s<1e-8 caught; fallback recomputes
// exactly). Saves ~25% of the per-edge VALU ops.
// Blocks 0..NSLOT-1 zero the BN partial-slot buffers for this layer's mm1.

__global__ __launch_bounds__(256) void k_edge(const u16* __restrict__ hin,
                                              const int* __restrict__ rowptr,
                                              const int* __restrict__ srcs,
                                              const float* __restrict__ tptr,
                                              u16* __restrict__ g,
                                              float* __restrict__ psum,
                                              float* __restrict__ pss, int N) {
    if (blockIdx.x < NSLOT) {    // zero BN partial slots for this layer's mm1
        psum[blockIdx.x * 256 + threadIdx.x] = 0.f;
        pss[blockIdx.x * 256 + threadIdx.x] = 0.f;
    }
    int u = blockIdx.x * 4 + (threadIdx.x >> 6);
    if (u >= N) return;
    u = __builtin_amdgcn_readfirstlane(u);   // wave-uniform -> SGPR
    int lane = threadIdx.x & 63;
    const u32* hin32 = (const u32*)hin;
    float t = *tptr;
    int beg = rowptr[u], end = rowptr[u + 1];   // scalar loads
    int cnt = end - beg;

    // own row: independent load, issued before the gather loop
    u32 pu = hin32[(size_t)u * 64 + lane];

    float s0 = 0.f, s1 = 0.f, sn0 = 0.f, sn1 = 0.f;

    for (int b = 0; b < cnt; b += 64) {
        int nb = cnt - b;
        if (nb > 64) nb = 64;
        // one coalesced load: lane l holds src index of edge (b+l)
        int sv = (b + lane < cnt) ? srcs[beg + b + lane] : 0;
        for (int ib = 0; ib < nb; ib += 16) {
            int m = nb - ib;
            if (m > 16) m = 16;
            u32 pr[16];
            #pragma unroll
            for (int j = 0; j < 16; ++j) {
                if (j < m) {
                    // uniform broadcast -> SGPR index -> scalar base address
                    int vi = __builtin_amdgcn_readlane(sv, ib + j);
                    pr[j] = hin32[(size_t)vi * 64 + lane];
                }
            }
            #pragma unroll
            for (int j = 0; j < 16; ++j) {
                if (j < m) {
                    u32 p = pr[j];
                    float v0 = fmaxf(blo(p), 0.f) + 1e-7f;
                    float v1 = fmaxf(bhi(p), 0.f) + 1e-7f;
                    float w0 = __expf(v0 * t), w1 = __expf(v1 * t);
                    s0 += w0; s1 += w1;
                    sn0 = fmaf(w0, v0, sn0);
                    sn1 = fmaf(w1, v1, sn1);
                }
            }
        }
    }

    bool has = (cnt > 0);
    // good iff sums in sane range and numerators finite (NaN-safe: any NaN
    // comparison yields false -> bad)
    bool good = (s0 >= 1e-8f) && (s0 <= 1e26f) && (s1 >= 1e-8f) && (s1 <= 1e26f)
                && (sn0 - sn0 == 0.0f) && (sn1 - sn1 == 0.0f);
    if (__any(has && !good)) {
        // exact online-softmax fallback (rare; correct for any t / magnitudes)
        float m0 = -3.0e38f, m1 = -3.0e38f;
        s0 = s1 = sn0 = sn1 = 0.f;
        for (int e = beg; e < end; ++e) {
            int v = srcs[e];
            u32 p = hin32[(size_t)v * 64 + lane];
            float v0 = fmaxf(blo(p), 0.f) + 1e-7f;
            float v1 = fmaxf(bhi(p), 0.f) + 1e-7f;
            float l0 = v0 * t, l1 = v1 * t;
            float nm0 = fmaxf(m0, l0), nm1 = fmaxf(m1, l1);
            float a0 = __expf(m0 - nm0), a1 = __expf(m1 - nm1);
            float w0 = __expf(l0 - nm0), w1 = __expf(l1 - nm1);
            s0 = s0 * a0 + w0;           s1 = s1 * a1 + w1;
            sn0 = sn0 * a0 + w0 * v0;    sn1 = sn1 * a1 + w1 * v1;
            m0 = nm0; m1 = nm1;
        }
    }

    float aggr0 = sn0 / (s0 + 1e-16f);
    float aggr1 = sn1 / (s1 + 1e-16f);
    float o0 = aggr0 + blo(pu);
    float o1 = aggr1 + bhi(pu);
    ((u32*)g)[(size_t)u * 64 + lane] = (u32)f2b(o0) | ((u32)f2b(o1) << 16);
}

// ---------------- mm1: h1 = g @ W1 (bf16 MFMA), fused BN partials ----------------
// 128x128 tile, 256 threads (4 waves), BK=64, K=128.
// Operand-swapped MFMA -> lane holds C[row][4 consecutive cols] -> 8B stores.
// BN partials: shfl_xor butterfly + one atomicAdd/col into NSLOT slot copies.

__global__ __launch_bounds__(256) void k_mm1(const u16* __restrict__ A,
                                             const u16* __restrict__ WT,
                                             u16* __restrict__ C,
                                             float* __restrict__ psum,
                                             float* __restrict__ pss, int M) {
    __shared__ u16 As[128][72];   // stride 144B: 2-way bank alias (free)
    __shared__ u16 Bs[128][72];
    __shared__ float csumA[128], cssA[128], csumB[128], cssB[128];
    int row0 = blockIdx.x * 128, n0 = blockIdx.y * 128;
    int tid = threadIdx.x;
    int lane = tid & 63, w = tid >> 6;
    int r0w = (w & 1) * 64, c0w = (w >> 1) * 64;
    int q = lane >> 4, ml = lane & 15;

    f32x4 acc[4][4];
    #pragma unroll
    for (int i = 0; i < 4; ++i)
        #pragma unroll
        for (int j = 0; j < 4; ++j) acc[i][j] = f32x4{0.f, 0.f, 0.f, 0.f};

    for (int kk = 0; kk < 128; kk += 64) {
        #pragma unroll
        for (int i = 0; i < 4; ++i) {
            int r = i * 32 + (tid >> 3);
            int c8 = (tid & 7) * 8;
            s16x8 va = s16x8{0, 0, 0, 0, 0, 0, 0, 0};
            if (row0 + r < M)
                va = *reinterpret_cast<const s16x8*>(&A[(size_t)(row0 + r) * 128 + kk + c8]);
            *reinterpret_cast<s16x8*>(&As[r][c8]) = va;
            s16x8 vb = *reinterpret_cast<const s16x8*>(&WT[(size_t)(n0 + r) * 128 + kk + c8]);
            *reinterpret_cast<s16x8*>(&Bs[r][c8]) = vb;
        }
        __syncthreads();
        #pragma unroll
        for (int ks = 0; ks < 64; ks += 32) {
            s16x8 af[4], bfr[4];
            #pragma unroll
            for (int rt = 0; rt < 4; ++rt)
                af[rt] = *reinterpret_cast<const s16x8*>(&As[r0w + rt * 16 + ml][ks + q * 8]);
            #pragma unroll
            for (int ct = 0; ct < 4; ++ct)
                bfr[ct] = *reinterpret_cast<const s16x8*>(&Bs[c0w + ct * 16 + ml][ks + q * 8]);
            #pragma unroll
            for (int rt = 0; rt < 4; ++rt)
                #pragma unroll
                for (int ct = 0; ct < 4; ++ct)
                    acc[rt][ct] = __builtin_amdgcn_mfma_f32_16x16x32_bf16(
                        bfr[ct], af[rt], acc[rt][ct], 0, 0, 0);  // swapped!
        }
        __syncthreads();
    }

    // ---- C stores: lane (q,ml) holds C[r0w+rt*16+ml][c0w+ct*16+q*4 .. +3] ----
    #pragma unroll
    for (int rt = 0; rt < 4; ++rt) {
        int row = row0 + r0w + rt * 16 + ml;
        if (row < M) {
            #pragma unroll
            for (int ct = 0; ct < 4; ++ct) {
                f32x4 a = acc[rt][ct];
                u32x2 p;
                p.x = (u32)f2b(a[0]) | ((u32)f2b(a[1]) << 16);
                p.y = (u32)f2b(a[2]) | ((u32)f2b(a[3]) << 16);
                int col = n0 + c0w + ct * 16 + q * 4;
                *reinterpret_cast<u32x2*>(&C[(size_t)row * H + col]) = p;
            }
        }
    }

    // ---- BN partials: per-lane col sums over its 4 rt-rows, butterfly over ml ----
    float sp[16], ssp[16];
    #pragma unroll
    for (int ct = 0; ct < 4; ++ct)
        #pragma unroll
        for (int r = 0; r < 4; ++r) {
            float s = 0.f, ss = 0.f;
            #pragma unroll
            for (int rt = 0; rt < 4; ++rt) {
                float v = acc[rt][ct][r];   // OOB rows staged as 0 -> contribute 0
                s += v;
                ss += v * v;
            }
            sp[ct * 4 + r] = s;
            ssp[ct * 4 + r] = ss;
        }
    #pragma unroll
    for (int msk = 1; msk < 16; msk <<= 1) {
        #pragma unroll
        for (int i = 0; i < 16; ++i) {
            sp[i] += __shfl_xor(sp[i], msk);
            ssp[i] += __shfl_xor(ssp[i], msk);
        }
    }
    if (ml == 0) {   // q-group leader: holds sums over this wave's 64 rows
        float* cs = (w & 1) ? csumB : csumA;
        float* cq = (w & 1) ? cssB : cssA;
        #pragma unroll
        for (int ct = 0; ct < 4; ++ct)
            #pragma unroll
            for (int r = 0; r < 4; ++r) {
                int col = c0w + ct * 16 + q * 4 + r;
                cs[col] = sp[ct * 4 + r];
                cq[col] = ssp[ct * 4 + r];
            }
    }
    __syncthreads();
    if (tid < 128) {
        int slot = blockIdx.x & (NSLOT - 1);
        atomicAdd(&psum[(size_t)slot * 256 + n0 + tid], csumA[tid] + csumB[tid]);
        atomicAdd(&pss[(size_t)slot * 256 + n0 + tid], cssA[tid] + cssB[tid]);
    }
}

// ---------------- mm2: out = relu(norm(h1)) @ W2 ----------------
// v6: BN finalize fused into the prologue (each block reduces the NSLOT slot
// copies -> LDS scale/shift; kills the 1-block k_bnfin dispatch). Norm+relu
// fused in A-stage; operand-swapped MFMA -> coalesced float4 / 8B stores.

__global__ __launch_bounds__(256) void k_mm2(const u16* __restrict__ H1,
                                             const float* __restrict__ psum,
                                             const float* __restrict__ pss,
                                             const float* __restrict__ gamma,
                                             const float* __restrict__ beta,
                                             const u16* __restrict__ WT,
                                             float* __restrict__ outf,
                                             u16* __restrict__ outb, int M) {
    __shared__ u16 As[128][72];
    __shared__ u16 Bs[128][72];
    __shared__ float sc_s[H], sh_s[H];
    int row0 = blockIdx.x * 128;
    int tid = threadIdx.x;
    int lane = tid & 63, w = tid >> 6;
    int r0w = (w & 1) * 64, c0w = (w >> 1) * 64;
    int q = lane >> 4, ml = lane & 15;

    // ---- fused BN finalize: reduce NSLOT slot copies for column tid ----
    {
        float s = 0.f, ss = 0.f;
        #pragma unroll 8
        for (int b = 0; b < NSLOT; ++b) {
            s += psum[b * 256 + tid];
            ss += pss[b * 256 + tid];
        }
        float inv = 1.0f / (float)M;
        float mean = s * inv;
        float var = ss * inv - mean * mean;
        if (var < 0.f) var = 0.f;
        float rstd = rsqrtf(var + 1e-5f);
        float sc = rstd * gamma[tid];
        sc_s[tid] = sc;
        sh_s[tid] = beta[tid] - mean * sc;
    }
    __syncthreads();

    f32x4 acc[4][4];
    #pragma unroll
    for (int i = 0; i < 4; ++i)
        #pragma unroll
        for (int j = 0; j < 4; ++j) acc[i][j] = f32x4{0.f, 0.f, 0.f, 0.f};

    for (int kk = 0; kk < 256; kk += 64) {
        #pragma unroll
        for (int i = 0; i < 4; ++i) {
            int r = i * 32 + (tid >> 3);
            int c8 = (tid & 7) * 8;
            s16x8 o = s16x8{0, 0, 0, 0, 0, 0, 0, 0};
            if (row0 + r < M) {
                s16x8 v = *reinterpret_cast<const s16x8*>(&H1[(size_t)(row0 + r) * H + kk + c8]);
                #pragma unroll
                for (int j = 0; j < 8; ++j) {
                    float f = b2f((u16)v[j]) * sc_s[kk + c8 + j] + sh_s[kk + c8 + j];
                    o[j] = (short)f2b(fmaxf(f, 0.f));
                }
            }
            *reinterpret_cast<s16x8*>(&As[r][c8]) = o;
            s16x8 vb = *reinterpret_cast<const s16x8*>(&WT[(size_t)r * H + kk + c8]);
            *reinterpret_cast<s16x8*>(&Bs[r][c8]) = vb;
        }
        __syncthreads();
        #pragma unroll
        for (int ks = 0; ks < 64; ks += 32) {
            s16x8 af[4], bfr[4];
            #pragma unroll
            for (int rt = 0; rt < 4; ++rt)
                af[rt] = *reinterpret_cast<const s16x8*>(&As[r0w + rt * 16 + ml][ks + q * 8]);
            #pragma unroll
            for (int ct = 0; ct < 4; ++ct)
                bfr[ct] = *reinterpret_cast<const s16x8*>(&Bs[c0w + ct * 16 + ml][ks + q * 8]);
            #pragma unroll
            for (int rt = 0; rt < 4; ++rt)
                #pragma unroll
                for (int ct = 0; ct < 4; ++ct)
                    acc[rt][ct] = __builtin_amdgcn_mfma_f32_16x16x32_bf16(
                        bfr[ct], af[rt], acc[rt][ct], 0, 0, 0);  // swapped!
        }
        __syncthreads();
    }

    #pragma unroll
    for (int rt = 0; rt < 4; ++rt) {
        int row = row0 + r0w + rt * 16 + ml;
        if (row < M) {
            #pragma unroll
            for (int ct = 0; ct < 4; ++ct) {
                f32x4 a = acc[rt][ct];
                int col = c0w + ct * 16 + q * 4;
                if (outb) {
                    u32x2 p;
                    p.x = (u32)f2b(fmaxf(a[0], 0.f)) | ((u32)f2b(fmaxf(a[1], 0.f)) << 16);
                    p.y = (u32)f2b(fmaxf(a[2], 0.f)) | ((u32)f2b(fmaxf(a[3], 0.f)) << 16);
                    *reinterpret_cast<u32x2*>(&outb[(size_t)row * D + col]) = p;
                } else {
                    *reinterpret_cast<f32x4*>(&outf[(size_t)row * D + col]) = a;
                }
            }
        }
    }
}

// ---------------- host launch ----------------

extern "C" void kernel_launch(void* const* d_in, const int* in_sizes, int n_in,
                              void* d_out, int out_size, void* d_ws, size_t ws_size,
                              hipStream_t stream) {
    const float* x         = (const float*)d_in[0];
    const int*   ei        = (const int*)d_in[1];
    const float* t_all     = (const float*)d_in[2];
    const float* W1_all    = (const float*)d_in[3];
    const float* W2_all    = (const float*)d_in[4];
    const float* gamma_all = (const float*)d_in[5];
    const float* beta_all  = (const float*)d_in[6];

    int N = in_sizes[0] / D;
    int E = in_sizes[1] / 2;
    float* out = (float*)d_out;

    char* ws = (char*)d_ws;
    size_t off = 0;
    auto alloc = [&](size_t bytes) -> void* {
        void* p = ws + off;
        off += (bytes + 255) & ~(size_t)255;
        return p;
    };
    int B = (N + 1023) >> 10;   // scan blocks
    int* rowptr = (int*)alloc((size_t)(N + 1) * 4);
    int* deg    = (int*)alloc((size_t)N * 4);
    int* srcs   = (int*)alloc((size_t)E * 4);
    int* bsum   = (int*)alloc((size_t)(B + 1) * 4);
    u16* xb     = (u16*)alloc((size_t)N * D * 2);
    u16* a0     = (u16*)alloc((size_t)N * D * 2);
    u16* a1     = (u16*)alloc((size_t)N * D * 2);
    u16* g      = (u16*)alloc((size_t)N * D * 2);
    u16* h1     = (u16*)alloc((size_t)N * H * 2);
    u16* WT1    = (u16*)alloc((size_t)4 * H * D * 2);
    u16* WT2    = (u16*)alloc((size_t)4 * D * H * 2);
    float* psum = (float*)alloc((size_t)NSLOT * 256 * 4);
    float* pss  = (float*)alloc((size_t)NSLOT * 256 * 4);
    (void)ws_size; (void)n_in; (void)out_size;

    const int* srcA = ei;
    const int* dstA = ei + E;

    // fused prep: bf16 cast + weight transposes + deg zero (one dispatch)
    int n4 = N * D / 4;
    k_cvtprep<<<(n4 + 262144 + 255) / 256, 256, 0, stream>>>(
        x, xb, W1_all, W2_all, WT1, WT2, deg, n4, N);

    // CSR build (hierarchical 3-phase scan; scan3 re-zeroes deg as scatter cnt)
    k_count<<<(E + 255) / 256, 256, 0, stream>>>(dstA, deg, E);
    k_scan1<<<B, 1024, 0, stream>>>(deg, rowptr, bsum, N);
    k_scan2<<<1, 1024, 0, stream>>>(bsum, B);
    k_scan3<<<(N + 1 + 1023) / 1024, 1024, 0, stream>>>(rowptr, bsum, deg, N, E);
    k_scatter<<<(E + 255) / 256, 256, 0, stream>>>(srcA, dstA, rowptr, deg, srcs, E);

    float* out0 = out;                  // mu
    float* out1 = out + (size_t)N * D;  // logstd

    int gx = (N + 127) / 128;
    for (int layer = 0; layer < 4; ++layer) {
        const u16* hin = (layer == 0) ? xb : (layer == 1 ? a0 : a1);
        k_edge<<<(N + 3) / 4, 256, 0, stream>>>(hin, rowptr, srcs, t_all + layer,
                                                g, psum, pss, N);

        k_mm1<<<dim3(gx, 2), 256, 0, stream>>>(g, WT1 + (size_t)layer * H * D, h1,
                                               psum, pss, N);

        float* outf = nullptr;
        u16*   outb = nullptr;
        if (layer == 0)      outb = a0;
        else if (layer == 1) outb = a1;
        else if (layer == 2) outf = out0;
        else                 outf = out1;

        k_mm2<<<dim3(gx, 1), 256, 0, stream>>>(h1, psum, pss,
                                               gamma_all + (size_t)layer * H,
                                               beta_all + (size_t)layer * H,
                                               WT2 + (size_t)layer * D * H,
                                               outf, outb, N);
    }
}